// Round 15
// baseline (313.104 us; speedup 1.0000x reference)
//
#include <hip/hip_runtime.h>
#include <hip/hip_bf16.h>
#include <stdint.h>

#define NE 8
#define T_TOK 4096
#define H_DIM 1024
#define I_DIM 4096
#define CAP 4096
#define RB128 72  // max total 128-row blocks: 8192/128 + 8 = 72

typedef __attribute__((ext_vector_type(8))) short bf16x8;
typedef __attribute__((ext_vector_type(4))) float f32x4;
typedef __attribute__((ext_vector_type(8))) unsigned short u16x8;

__device__ __forceinline__ unsigned short f2bf(float f) {
  __hip_bfloat16 h = __float2bfloat16(f);
  return *reinterpret_cast<unsigned short*>(&h);
}

__device__ __forceinline__ void lds_load16(const void* g, void* l) {
  __builtin_amdgcn_global_load_lds((__attribute__((address_space(1))) void*)g,
                                   (__attribute__((address_space(3))) void*)l,
                                   16, 0, 0);
}

// swizzled LDS fragment read: tile layout [rows][64 bf16] (128B rows, 8x16B
// chunks); content chunk cc of row lives at physical chunk cc ^ (row&7)
__device__ __forceinline__ const bf16x8* lds_frag(const char* base, int row,
                                                  int cc) {
  return (const bf16x8*)(base + row * 128 + ((cc ^ (row & 7)) << 4));
}

// bijective XCD swizzle (nwg % 8 == 0): each XCD owns a contiguous logical chunk
__device__ __forceinline__ int xcd_swz(int bid, int nwg) {
  return (bid & 7) * (nwg >> 3) + (bid >> 3);
}

// map flat 128-row block g -> (expert e, local block mb); rowbase is 128*g
__device__ __forceinline__ bool rb_lookup(const int* counts, int g, int* e_out,
                                          int* mb_out, int* cnt_out) {
  int acc = 0;
#pragma unroll
  for (int i = 0; i < NE; ++i) {
    int c = counts[i];
    int rb = (c + 127) >> 7;
    if (g < acc + rb) {
      *e_out = i;
      *mb_out = g - acc;
      *cnt_out = c;
      return true;
    }
    acc += rb;
  }
  return false;
}

// map flat 64-row block g2 (within the 128-padded slot layout) -> (e, rowbase)
__device__ __forceinline__ bool rb_lookup64(const int* counts, int g2,
                                            int* e_out, int* rowbase) {
  int acc = 0, base = 0;
#pragma unroll
  for (int i = 0; i < NE; ++i) {
    int c = counts[i];
    int rb = ((c + 127) >> 7) * 2;  // 64-row blocks in this expert's region
    if (g2 < acc + rb) {
      *e_out = i;
      *rowbase = base + (g2 - acc) * 64;
      return true;
    }
    acc += rb;
    base += (c + 127) & ~127;
  }
  return false;
}

// 64x64 transpose+convert tile: src f32 [R][C] region (r0,c0) -> dst bf16
// [C][R]. MLP-staged: all 4 float4 loads issued before LDS writes.
__device__ __forceinline__ void transpose_tile(const float* __restrict__ s,
                                               unsigned short* __restrict__ d,
                                               int R, int C, int r0, int c0,
                                               char* shm, int tid) {
  float(*tile)[65] = (float(*)[65])shm;
  const int lr = tid >> 4, lc = (tid & 15) << 2;
  float4 vv[4];
#pragma unroll
  for (int j = 0; j < 4; ++j)
    vv[j] = *reinterpret_cast<const float4*>(
        &s[(size_t)(r0 + j * 16 + lr) * C + c0 + lc]);
#pragma unroll
  for (int j = 0; j < 4; ++j) {
    tile[j * 16 + lr][lc + 0] = vv[j].x;
    tile[j * 16 + lr][lc + 1] = vv[j].y;
    tile[j * 16 + lr][lc + 2] = vv[j].z;
    tile[j * 16 + lr][lc + 3] = vv[j].w;
  }
  __syncthreads();
  const int oc = tid >> 3, orr = (tid & 7) << 3;
#pragma unroll
  for (int j = 0; j < 2; ++j) {
    int c = j * 32 + oc;
    u16x8 o;
#pragma unroll
    for (int k = 0; k < 8; ++k) o[k] = f2bf(tile[orr + k][c]);
    *reinterpret_cast<u16x8*>(&d[(size_t)(c0 + c) * R + r0 + orr]) = o;
  }
}

// ---------------- K1: router (NO atomics) U w_in transpose ----
__global__ void __launch_bounds__(256) prep_kernel(
    const float* __restrict__ x, const float* __restrict__ rw,
    int* __restrict__ top2e, float* __restrict__ wtok,
    unsigned short* __restrict__ xb, const float* __restrict__ w_in,
    unsigned short* __restrict__ win_t) {
  __shared__ char shm[16640];  // transpose tile; router uses first 128B
  const int bid = blockIdx.x;
  const int tid = threadIdx.x;

  if (bid < T_TOK) {
    // ---- router + x->bf16 for token t ----
    const int t = bid;
    float(*red)[NE] = (float(*)[NE])shm;
    float4 v = reinterpret_cast<const float4*>(x + (size_t)t * H_DIM)[tid];
    ushort4 o;
    o.x = f2bf(v.x); o.y = f2bf(v.y); o.z = f2bf(v.z); o.w = f2bf(v.w);
    reinterpret_cast<ushort4*>(xb + (size_t)t * H_DIM)[tid] = o;

    float part[NE];
#pragma unroll
    for (int e = 0; e < NE; ++e) {
      float4 w = reinterpret_cast<const float4*>(rw + (size_t)e * H_DIM)[tid];
      part[e] = v.x * w.x + v.y * w.y + v.z * w.z + v.w * w.w;
    }
    const int wave = tid >> 6, lane = tid & 63;
#pragma unroll
    for (int e = 0; e < NE; ++e) {
#pragma unroll
      for (int off = 32; off > 0; off >>= 1)
        part[e] += __shfl_xor(part[e], off);
    }
    if (lane == 0) {
#pragma unroll
      for (int e = 0; e < NE; ++e) red[wave][e] = part[e];
    }
    __syncthreads();
    if (tid == 0) {
      float acc[NE];
#pragma unroll
      for (int e = 0; e < NE; ++e)
        acc[e] = red[0][e] + red[1][e] + red[2][e] + red[3][e];
      int i0 = 0;
#pragma unroll
      for (int e = 1; e < NE; ++e)
        if (acc[e] > acc[i0]) i0 = e;
      int i1 = (i0 == 0) ? 1 : 0;
#pragma unroll
      for (int e = 0; e < NE; ++e)
        if (e != i0 && acc[e] > acc[i1]) i1 = e;
      float la = acc[i0], lb = acc[i1];
      float r = expf(lb - la);          // <= 1
      float wa = 1.f / (1.f + r);       // normalized top-2 softmax weights
      float wb = 1.f - wa;
      top2e[2 * t + 0] = i0;
      wtok[2 * t + 0] = wa;
      top2e[2 * t + 1] = i1;
      wtok[2 * t + 1] = wb;
    }
  } else {
    // ---- w_in [e][1024][4096] -> win_t [e][4096][1024] ----
    const int idx = bid - T_TOK;
    const int e = idx >> 10, rem = idx & 1023;
    const int c0 = (rem & 63) * 64, r0 = (rem >> 6) * 64;  // C=4096, R=1024
    transpose_tile(w_in + (size_t)e * H_DIM * I_DIM,
                   win_t + (size_t)e * H_DIM * I_DIM, H_DIM, I_DIM, r0, c0,
                   shm, tid);
  }
}

// ---------------- bucketize: deterministic counting-rank, no atomics ----
__global__ void __launch_bounds__(1024) bucketize_kernel(
    const int* __restrict__ top2e, int* __restrict__ counts,
    int* __restrict__ perm, int* __restrict__ se) {
  const int e = blockIdx.x;
  const int tid = threadIdx.x;
  __shared__ int wsum[16];
  int my[8];
  int cnt = 0;
#pragma unroll
  for (int j = 0; j < 8; ++j) {
    my[j] = top2e[tid * 8 + j];
    cnt += (my[j] == e) ? 1 : 0;
  }
  const int lane = tid & 63, wave = tid >> 6;
  int scan = cnt;  // inclusive wave scan
#pragma unroll
  for (int off = 1; off < 64; off <<= 1) {
    int v = __shfl_up(scan, off);
    if (lane >= off) scan += v;
  }
  if (lane == 63) wsum[wave] = scan;
  __syncthreads();
  int wbase = 0;
#pragma unroll
  for (int w = 0; w < 16; ++w)
    if (w < wave) wbase += wsum[w];
  int pos = wbase + scan - cnt;  // exclusive prefix for this thread
#pragma unroll
  for (int j = 0; j < 8; ++j) {
    if (my[j] == e) {
      int entry = tid * 8 + j;
      perm[e * CAP + pos] = entry >> 1;
      se[entry] = (e << 20) | pos;
      ++pos;
    }
  }
  if (tid == 1023) counts[e] = pos;
}

// ---------------- K2: ffn1 (2304 blocks, first) U w_out transpose (8192) ----
__global__ void __launch_bounds__(256, 3) ffn1_wout_kernel(
    const unsigned short* __restrict__ xb,
    const unsigned short* __restrict__ win_t,  // [E][I][H]
    const float* __restrict__ b_in,            // [E][I]
    const int* __restrict__ counts,
    const int* __restrict__ perm,
    unsigned short* __restrict__ inter,
    const float* __restrict__ w_out,
    unsigned short* __restrict__ wout_t) {
  __shared__ char smem[32768];
  const int bid = blockIdx.x;
  const int tid = threadIdx.x;

  if (bid >= 32 * RB128) {
    // ---- w_out [e][4096][1024] -> wout_t [e][1024][4096] ----
    const int idx = bid - 32 * RB128;
    const int e = idx >> 10, rem = idx & 1023;
    const int c0 = (rem & 15) * 64, r0 = (rem >> 4) * 64;  // C=1024, R=4096
    transpose_tile(w_out + (size_t)e * H_DIM * I_DIM,
                   wout_t + (size_t)e * H_DIM * I_DIM, I_DIM, H_DIM, r0, c0,
                   smem, tid);
    return;
  }

  const int logical = xcd_swz(bid, 32 * RB128);
  const int nb = logical / RB128;  // 0..31, consecutive logicals share B panel
  const int g = logical % RB128;
  int e, mb, cnt;
  if (!rb_lookup(counts, g, &e, &mb, &cnt)) return;

  int tokr[4];
#pragma unroll
  for (int it = 0; it < 4; ++it) {
    int r = (it * 256 + tid) >> 3;  // 0..127
    tokr[it] = perm[e * CAP + min(mb * 128 + r, cnt - 1)];
  }

  const int wave = tid >> 6, lane = tid & 63;
  const int wr = wave >> 1, wn = wave & 1;  // 2M x 2N
  const int l16 = lane & 15, l4 = lane >> 4;
  const unsigned short* Bbase =
      win_t + (size_t)e * I_DIM * H_DIM + (size_t)(nb * 128) * H_DIM;

  f32x4 acc[4][4] = {};

  const int NK = H_DIM / 64;  // 16
  for (int kt = 0; kt < NK; ++kt) {
    __syncthreads();  // all waves done reading smem (prev iter)
#pragma unroll
    for (int it = 0; it < 4; ++it) {
      int id = it * 256 + tid;
      int r = id >> 3;
      int cs = (id & 7) ^ (r & 7);  // T2: pre-swizzled source chunk
      lds_load16(xb + (size_t)tokr[it] * H_DIM + kt * 64 + cs * 8,
                 smem + id * 16);
      lds_load16(Bbase + (size_t)r * H_DIM + kt * 64 + cs * 8,
                 smem + 16384 + id * 16);
    }
    __syncthreads();  // compiler drains vmcnt(0) here (m97 asm behavior)
#pragma unroll
    for (int kk = 0; kk < 2; ++kk) {
      bf16x8 af[4], bv[4];
#pragma unroll
      for (int m = 0; m < 4; ++m)
        af[m] = *lds_frag(smem, wr * 64 + m * 16 + l16, kk * 4 + l4);
#pragma unroll
      for (int n = 0; n < 4; ++n)
        bv[n] = *lds_frag(smem + 16384, wn * 64 + n * 16 + l16, kk * 4 + l4);
#pragma unroll
      for (int m = 0; m < 4; ++m)
#pragma unroll
        for (int n = 0; n < 4; ++n)
          acc[m][n] =
              __builtin_amdgcn_mfma_f32_16x16x32_bf16(af[m], bv[n], acc[m][n], 0, 0, 0);
    }
  }

  // ---- epilogue: GELU, coalesce via per-wave 8KB LDS slice ----
  __syncthreads();  // all waves done with staging LDS
  const size_t rowbase = (size_t)g * 128;
  unsigned short* slice = (unsigned short*)(smem + wave * 8192);
#pragma unroll
  for (int n = 0; n < 4; ++n) {
    float bias = b_in[e * I_DIM + nb * 128 + wn * 64 + n * 16 + l16];
#pragma unroll
    for (int m = 0; m < 4; ++m) {
#pragma unroll
      for (int j = 0; j < 4; ++j) {
        float v = acc[m][n][j] + bias;
        // tanh-form GELU: v * sigmoid(1.59577(v + 0.044715 v^3)); |err| <~1e-3
        float t = __expf(-1.5957691216057308f * v - 0.07135481627f * v * v * v);
        float gg = v / (1.f + t);
        slice[(m * 16 + l4 * 4 + j) * 64 + n * 16 + l16] = f2bf(gg);
      }
    }
  }
  __syncthreads();  // slice writes visible before cross-lane readback
#pragma unroll
  for (int it = 0; it < 8; ++it) {
    int row = it * 8 + (lane >> 3);        // 0..63
    int colb = (lane & 7) * 8;             // 8 bf16 = 16B
    u16x8 v = *(const u16x8*)&slice[row * 64 + colb];
    *(u16x8*)&inter[(rowbase + wr * 64 + row) * (size_t)I_DIM + nb * 128 +
                    wn * 64 + colb] = v;
  }
}

// ---------------- FFN2: y[slot] = inter @ w_out + b_out (dense, no atomics) --
// M-split: 64x128 tile, BK=64, 256 thr (4 waves 2Mx2N, 32x64/wave), 32KB LDS
// (24KB staging). ~1056 active blocks = 4.1/CU -> multi-block overlap hides
// the barrier drain + dirty-L2 wout_t latency. A-MAJOR grid (g2-major).
__global__ void __launch_bounds__(256, 4) ffn2_kernel(
    const unsigned short* __restrict__ inter,
    const unsigned short* __restrict__ wout_t,  // [E][H][I]
    const float* __restrict__ b_out,            // [E][H]
    const int* __restrict__ counts,
    float* __restrict__ y) {                    // [slot][H]
  const int logical = xcd_swz(blockIdx.x, RB128 * 16);
  const int g2 = logical >> 3;     // consecutive logicals share A panel
  const int nb = logical & 7;
  int e, rowbase_i;
  if (!rb_lookup64(counts, g2, &e, &rowbase_i)) return;
  const size_t rowbase = (size_t)rowbase_i;

  __shared__ char smem[32768];  // A 8KB | B 16KB staging; 4x8KB epi slices

  const int tid = threadIdx.x;
  const int wave = tid >> 6, lane = tid & 63;
  const int wr = wave >> 1, wn = wave & 1;  // 2M x 2N (32 rows x 64 cols/wave)
  const int l16 = lane & 15, l4 = lane >> 4;
  const unsigned short* Bbase =
      wout_t + (size_t)e * H_DIM * I_DIM + (size_t)(nb * 128) * I_DIM;

  f32x4 acc[2][4] = {};

  const int NK = I_DIM / 64;  // 64
  for (int kt = 0; kt < NK; ++kt) {
    __syncthreads();
#pragma unroll
    for (int it = 0; it < 2; ++it) {  // A: 64 rows x 64 cols = 8KB
      int id = it * 256 + tid;
      int r = id >> 3;
      int cs = (id & 7) ^ (r & 7);
      lds_load16(inter + (rowbase + r) * (size_t)I_DIM + kt * 64 + cs * 8,
                 smem + id * 16);
    }
#pragma unroll
    for (int it = 0; it < 4; ++it) {  // B: 128 rows x 64 cols = 16KB
      int id = it * 256 + tid;
      int r = id >> 3;
      int cs = (id & 7) ^ (r & 7);
      lds_load16(Bbase + (size_t)r * I_DIM + kt * 64 + cs * 8,
                 smem + 8192 + id * 16);
    }
    __syncthreads();
#pragma unroll
    for (int kk = 0; kk < 2; ++kk) {
      bf16x8 af[2], bv[4];
#pragma unroll
      for (int m = 0; m < 2; ++m)
        af[m] = *lds_frag(smem, wr * 32 + m * 16 + l16, kk * 4 + l4);
#pragma unroll
      for (int n = 0; n < 4; ++n)
        bv[n] = *lds_frag(smem + 8192, wn * 64 + n * 16 + l16, kk * 4 + l4);
#pragma unroll
      for (int m = 0; m < 2; ++m)
#pragma unroll
        for (int n = 0; n < 4; ++n)
          acc[m][n] =
              __builtin_amdgcn_mfma_f32_16x16x32_bf16(af[m], bv[n], acc[m][n], 0, 0, 0);
    }
  }

  // ---- epilogue: per-wave 32x64 f32 slice (8KB), coalesced 16B stores ----
  __syncthreads();
  float* slice = (float*)(smem + wave * 8192);
#pragma unroll
  for (int n = 0; n < 4; ++n) {
    float bias = b_out[e * H_DIM + nb * 128 + wn * 64 + n * 16 + l16];
#pragma unroll
    for (int m = 0; m < 2; ++m) {
#pragma unroll
      for (int j = 0; j < 4; ++j) {
        slice[(m * 16 + l4 * 4 + j) * 64 + n * 16 + l16] = acc[m][n][j] + bias;
      }
    }
  }
  __syncthreads();  // slice writes visible before cross-lane readback
#pragma unroll
  for (int it = 0; it < 8; ++it) {
    int row = it * 4 + (lane >> 4);      // 0..31
    int col = (lane & 15) * 4;           // 4 floats = 16B
    float4 v = *(const float4*)&slice[row * 64 + col];
    *(float4*)&y[(rowbase + wr * 32 + row) * (size_t)H_DIM + nb * 128 +
                 wn * 64 + col] = v;
  }
}

// ---------------- combine: out[t] = w0*y[slot0] + w1*y[slot1] ---------------
__global__ void __launch_bounds__(256) combine_kernel(
    const float* __restrict__ y, const int* __restrict__ counts,
    const int* __restrict__ se, const float* __restrict__ wtok,
    float* __restrict__ out) {
  const int t = blockIdx.x;
  int poff[NE];
  int run = 0;
#pragma unroll
  for (int e = 0; e < NE; ++e) {
    poff[e] = run;
    run += (counts[e] + 127) & ~127;  // must match 128-row block padding
  }
  int c0 = se[2 * t], c1 = se[2 * t + 1];
  float w0 = wtok[2 * t], w1 = wtok[2 * t + 1];
  const float* y0 = y + (size_t)(poff[c0 >> 20] + (c0 & 0xFFFFF)) * H_DIM;
  const float* y1 = y + (size_t)(poff[c1 >> 20] + (c1 & 0xFFFFF)) * H_DIM;
  int h = threadIdx.x * 4;
  float4 a = *reinterpret_cast<const float4*>(y0 + h);
  float4 b = *reinterpret_cast<const float4*>(y1 + h);
  float4 o;
  o.x = w0 * a.x + w1 * b.x;
  o.y = w0 * a.y + w1 * b.y;
  o.z = w0 * a.z + w1 * b.z;
  o.w = w0 * a.w + w1 * b.w;
  *reinterpret_cast<float4*>(out + (size_t)t * H_DIM + h) = o;
}

extern "C" void kernel_launch(void* const* d_in, const int* in_sizes, int n_in,
                              void* d_out, int out_size, void* d_ws, size_t ws_size,
                              hipStream_t stream) {
  const float* x     = (const float*)d_in[0];
  const float* rw    = (const float*)d_in[1];
  const float* w_in  = (const float*)d_in[2];
  const float* b_in  = (const float*)d_in[3];
  const float* w_out = (const float*)d_in[4];
  const float* b_out = (const float*)d_in[5];
  float* out = (float*)d_out;

  char* ws = (char*)d_ws;
  size_t off = 0;
  auto alloc = [&](size_t bytes) {
    char* p = ws + off;
    off = (off + bytes + 255) & ~(size_t)255;
    return p;
  };
  int* counts            = (int*)alloc(NE * 4);
  int* perm              = (int*)alloc((size_t)NE * CAP * 4);
  int* top2e             = (int*)alloc((size_t)T_TOK * 2 * 4);
  int* se                = (int*)alloc((size_t)T_TOK * 2 * 4);
  float* wtok            = (float*)alloc((size_t)T_TOK * 2 * 4);
  unsigned short* xb     = (unsigned short*)alloc((size_t)T_TOK * H_DIM * 2);
  unsigned short* win_t  = (unsigned short*)alloc((size_t)NE * H_DIM * I_DIM * 2);
  unsigned short* wout_t = (unsigned short*)alloc((size_t)NE * H_DIM * I_DIM * 2);
  unsigned short* inter  = (unsigned short*)alloc((size_t)(T_TOK * 2 + NE * 256) * I_DIM * 2);
  // y overlays ONLY win_t (read-dead after K2's ffn1 part; rewritten by K1's
  // transpose before the next ffn1): need <= 9216*1024*4 = 37.7MB <= 64MB
  float* y = (float*)win_t;
  if (off > ws_size) return;  // ws too small -> visible correctness failure

  prep_kernel<<<T_TOK + NE * 1024, 256, 0, stream>>>(x, rw, top2e, wtok, xb,
                                                     w_in, win_t);
  bucketize_kernel<<<NE, 1024, 0, stream>>>(top2e, counts, perm, se);
  ffn1_wout_kernel<<<32 * RB128 + NE * 1024, 256, 0, stream>>>(
      xb, win_t, b_in, counts, perm, inter, w_out, wout_t);
  ffn2_kernel<<<RB128 * 16, 256, 0, stream>>>(inter, wout_t, b_out, counts, y);
  combine_kernel<<<T_TOK, 256, 0, stream>>>(y, counts, se, wtok, out);
}

// Round 16
// 291.299 us; speedup vs baseline: 1.0749x; 1.0749x over previous
//
#include <hip/hip_runtime.h>
#include <hip/hip_bf16.h>
#include <stdint.h>

#define NE 8
#define T_TOK 4096
#define H_DIM 1024
#define I_DIM 4096
#define CAP 4096
#define RB128 72    // max total 128-row blocks: 8192/128 + 8 = 72
#define YSLOTS 9216 // max padded slot rows: 8192 + 8*127 -> round to 9216

typedef __attribute__((ext_vector_type(8))) short bf16x8;
typedef __attribute__((ext_vector_type(4))) float f32x4;
typedef __attribute__((ext_vector_type(8))) unsigned short u16x8;

__device__ __forceinline__ unsigned short f2bf(float f) {
  __hip_bfloat16 h = __float2bfloat16(f);
  return *reinterpret_cast<unsigned short*>(&h);
}

__device__ __forceinline__ void lds_load16(const void* g, void* l) {
  __builtin_amdgcn_global_load_lds((__attribute__((address_space(1))) void*)g,
                                   (__attribute__((address_space(3))) void*)l,
                                   16, 0, 0);
}

// swizzled LDS fragment read: tile layout [rows][64 bf16] (128B rows, 8x16B
// chunks); content chunk cc of row lives at physical chunk cc ^ (row&7)
__device__ __forceinline__ const bf16x8* lds_frag(const char* base, int row,
                                                  int cc) {
  return (const bf16x8*)(base + row * 128 + ((cc ^ (row & 7)) << 4));
}

// bijective XCD swizzle (nwg % 8 == 0): each XCD owns a contiguous logical chunk
__device__ __forceinline__ int xcd_swz(int bid, int nwg) {
  return (bid & 7) * (nwg >> 3) + (bid >> 3);
}

// map flat 128-row block g -> (expert e, local block mb); rowbase is 128*g
__device__ __forceinline__ bool rb_lookup(const int* counts, int g, int* e_out,
                                          int* mb_out, int* cnt_out) {
  int acc = 0;
#pragma unroll
  for (int i = 0; i < NE; ++i) {
    int c = counts[i];
    int rb = (c + 127) >> 7;
    if (g < acc + rb) {
      *e_out = i;
      *mb_out = g - acc;
      *cnt_out = c;
      return true;
    }
    acc += rb;
  }
  return false;
}

// 64x64 transpose+convert tile: src f32 [R][C] region (r0,c0) -> dst bf16
// [C][R]. MLP-staged: all 4 float4 loads issued before LDS writes.
__device__ __forceinline__ void transpose_tile(const float* __restrict__ s,
                                               unsigned short* __restrict__ d,
                                               int R, int C, int r0, int c0,
                                               char* shm, int tid) {
  float(*tile)[65] = (float(*)[65])shm;
  const int lr = tid >> 4, lc = (tid & 15) << 2;
  float4 vv[4];
#pragma unroll
  for (int j = 0; j < 4; ++j)
    vv[j] = *reinterpret_cast<const float4*>(
        &s[(size_t)(r0 + j * 16 + lr) * C + c0 + lc]);
#pragma unroll
  for (int j = 0; j < 4; ++j) {
    tile[j * 16 + lr][lc + 0] = vv[j].x;
    tile[j * 16 + lr][lc + 1] = vv[j].y;
    tile[j * 16 + lr][lc + 2] = vv[j].z;
    tile[j * 16 + lr][lc + 3] = vv[j].w;
  }
  __syncthreads();
  const int oc = tid >> 3, orr = (tid & 7) << 3;
#pragma unroll
  for (int j = 0; j < 2; ++j) {
    int c = j * 32 + oc;
    u16x8 o;
#pragma unroll
    for (int k = 0; k < 8; ++k) o[k] = f2bf(tile[orr + k][c]);
    *reinterpret_cast<u16x8*>(&d[(size_t)(c0 + c) * R + r0 + orr]) = o;
  }
}

// ---------------- K1: router (NO atomics) U w_in transpose ----
__global__ void __launch_bounds__(256) prep_kernel(
    const float* __restrict__ x, const float* __restrict__ rw,
    int* __restrict__ top2e, float* __restrict__ wtok,
    unsigned short* __restrict__ xb, const float* __restrict__ w_in,
    unsigned short* __restrict__ win_t) {
  __shared__ char shm[16640];  // transpose tile; router uses first 128B
  const int bid = blockIdx.x;
  const int tid = threadIdx.x;

  if (bid < T_TOK) {
    // ---- router + x->bf16 for token t ----
    const int t = bid;
    float(*red)[NE] = (float(*)[NE])shm;
    float4 v = reinterpret_cast<const float4*>(x + (size_t)t * H_DIM)[tid];
    ushort4 o;
    o.x = f2bf(v.x); o.y = f2bf(v.y); o.z = f2bf(v.z); o.w = f2bf(v.w);
    reinterpret_cast<ushort4*>(xb + (size_t)t * H_DIM)[tid] = o;

    float part[NE];
#pragma unroll
    for (int e = 0; e < NE; ++e) {
      float4 w = reinterpret_cast<const float4*>(rw + (size_t)e * H_DIM)[tid];
      part[e] = v.x * w.x + v.y * w.y + v.z * w.z + v.w * w.w;
    }
    const int wave = tid >> 6, lane = tid & 63;
#pragma unroll
    for (int e = 0; e < NE; ++e) {
#pragma unroll
      for (int off = 32; off > 0; off >>= 1)
        part[e] += __shfl_xor(part[e], off);
    }
    if (lane == 0) {
#pragma unroll
      for (int e = 0; e < NE; ++e) red[wave][e] = part[e];
    }
    __syncthreads();
    if (tid == 0) {
      float acc[NE];
#pragma unroll
      for (int e = 0; e < NE; ++e)
        acc[e] = red[0][e] + red[1][e] + red[2][e] + red[3][e];
      int i0 = 0;
#pragma unroll
      for (int e = 1; e < NE; ++e)
        if (acc[e] > acc[i0]) i0 = e;
      int i1 = (i0 == 0) ? 1 : 0;
#pragma unroll
      for (int e = 0; e < NE; ++e)
        if (e != i0 && acc[e] > acc[i1]) i1 = e;
      float la = acc[i0], lb = acc[i1];
      float r = expf(lb - la);          // <= 1
      float wa = 1.f / (1.f + r);       // normalized top-2 softmax weights
      float wb = 1.f - wa;
      top2e[2 * t + 0] = i0;
      wtok[2 * t + 0] = wa;
      top2e[2 * t + 1] = i1;
      wtok[2 * t + 1] = wb;
    }
  } else {
    // ---- w_in [e][1024][4096] -> win_t [e][4096][1024] ----
    const int idx = bid - T_TOK;
    const int e = idx >> 10, rem = idx & 1023;
    const int c0 = (rem & 63) * 64, r0 = (rem >> 6) * 64;  // C=4096, R=1024
    transpose_tile(w_in + (size_t)e * H_DIM * I_DIM,
                   win_t + (size_t)e * H_DIM * I_DIM, H_DIM, I_DIM, r0, c0,
                   shm, tid);
  }
}

// ---------------- bucketize: deterministic counting-rank, no atomics ----
__global__ void __launch_bounds__(1024) bucketize_kernel(
    const int* __restrict__ top2e, int* __restrict__ counts,
    int* __restrict__ perm, int* __restrict__ se) {
  const int e = blockIdx.x;
  const int tid = threadIdx.x;
  __shared__ int wsum[16];
  int my[8];
  int cnt = 0;
#pragma unroll
  for (int j = 0; j < 8; ++j) {
    my[j] = top2e[tid * 8 + j];
    cnt += (my[j] == e) ? 1 : 0;
  }
  const int lane = tid & 63, wave = tid >> 6;
  int scan = cnt;  // inclusive wave scan
#pragma unroll
  for (int off = 1; off < 64; off <<= 1) {
    int v = __shfl_up(scan, off);
    if (lane >= off) scan += v;
  }
  if (lane == 63) wsum[wave] = scan;
  __syncthreads();
  int wbase = 0;
#pragma unroll
  for (int w = 0; w < 16; ++w)
    if (w < wave) wbase += wsum[w];
  int pos = wbase + scan - cnt;  // exclusive prefix for this thread
#pragma unroll
  for (int j = 0; j < 8; ++j) {
    if (my[j] == e) {
      int entry = tid * 8 + j;
      perm[e * CAP + pos] = entry >> 1;
      se[entry] = (e << 20) | pos;
      ++pos;
    }
  }
  if (tid == 1023) counts[e] = pos;
}

// ---------------- K2: ffn1 (2304 blocks, first) U w_out transpose (8192) ----
__global__ void __launch_bounds__(256, 3) ffn1_wout_kernel(
    const unsigned short* __restrict__ xb,
    const unsigned short* __restrict__ win_t,  // [E][I][H]
    const float* __restrict__ b_in,            // [E][I]
    const int* __restrict__ counts,
    const int* __restrict__ perm,
    unsigned short* __restrict__ inter,
    const float* __restrict__ w_out,
    unsigned short* __restrict__ wout_t) {
  __shared__ char smem[32768];
  const int bid = blockIdx.x;
  const int tid = threadIdx.x;

  if (bid >= 32 * RB128) {
    // ---- w_out [e][4096][1024] -> wout_t [e][1024][4096] ----
    const int idx = bid - 32 * RB128;
    const int e = idx >> 10, rem = idx & 1023;
    const int c0 = (rem & 15) * 64, r0 = (rem >> 4) * 64;  // C=1024, R=4096
    transpose_tile(w_out + (size_t)e * H_DIM * I_DIM,
                   wout_t + (size_t)e * H_DIM * I_DIM, I_DIM, H_DIM, r0, c0,
                   smem, tid);
    return;
  }

  const int logical = xcd_swz(bid, 32 * RB128);
  const int nb = logical / RB128;  // 0..31, consecutive logicals share B panel
  const int g = logical % RB128;
  int e, mb, cnt;
  if (!rb_lookup(counts, g, &e, &mb, &cnt)) return;

  int tokr[4];
#pragma unroll
  for (int it = 0; it < 4; ++it) {
    int r = (it * 256 + tid) >> 3;  // 0..127
    tokr[it] = perm[e * CAP + min(mb * 128 + r, cnt - 1)];
  }

  const int wave = tid >> 6, lane = tid & 63;
  const int wr = wave >> 1, wn = wave & 1;  // 2M x 2N
  const int l16 = lane & 15, l4 = lane >> 4;
  const unsigned short* Bbase =
      win_t + (size_t)e * I_DIM * H_DIM + (size_t)(nb * 128) * H_DIM;

  f32x4 acc[4][4] = {};

  const int NK = H_DIM / 64;  // 16
  for (int kt = 0; kt < NK; ++kt) {
    __syncthreads();  // all waves done reading smem (prev iter)
#pragma unroll
    for (int it = 0; it < 4; ++it) {
      int id = it * 256 + tid;
      int r = id >> 3;
      int cs = (id & 7) ^ (r & 7);  // T2: pre-swizzled source chunk
      lds_load16(xb + (size_t)tokr[it] * H_DIM + kt * 64 + cs * 8,
                 smem + id * 16);
      lds_load16(Bbase + (size_t)r * H_DIM + kt * 64 + cs * 8,
                 smem + 16384 + id * 16);
    }
    __syncthreads();  // compiler drains vmcnt(0) here (m97 asm behavior)
#pragma unroll
    for (int kk = 0; kk < 2; ++kk) {
      bf16x8 af[4], bv[4];
#pragma unroll
      for (int m = 0; m < 4; ++m)
        af[m] = *lds_frag(smem, wr * 64 + m * 16 + l16, kk * 4 + l4);
#pragma unroll
      for (int n = 0; n < 4; ++n)
        bv[n] = *lds_frag(smem + 16384, wn * 64 + n * 16 + l16, kk * 4 + l4);
#pragma unroll
      for (int m = 0; m < 4; ++m)
#pragma unroll
        for (int n = 0; n < 4; ++n)
          acc[m][n] =
              __builtin_amdgcn_mfma_f32_16x16x32_bf16(af[m], bv[n], acc[m][n], 0, 0, 0);
    }
  }

  // ---- epilogue: GELU, coalesce via per-wave 8KB LDS slice ----
  __syncthreads();  // all waves done with staging LDS
  const size_t rowbase = (size_t)g * 128;
  unsigned short* slice = (unsigned short*)(smem + wave * 8192);
#pragma unroll
  for (int n = 0; n < 4; ++n) {
    float bias = b_in[e * I_DIM + nb * 128 + wn * 64 + n * 16 + l16];
#pragma unroll
    for (int m = 0; m < 4; ++m) {
#pragma unroll
      for (int j = 0; j < 4; ++j) {
        float v = acc[m][n][j] + bias;
        // tanh-form GELU: v * sigmoid(1.59577(v + 0.044715 v^3)); |err| <~1e-3
        float t = __expf(-1.5957691216057308f * v - 0.07135481627f * v * v * v);
        float gg = v / (1.f + t);
        slice[(m * 16 + l4 * 4 + j) * 64 + n * 16 + l16] = f2bf(gg);
      }
    }
  }
  __syncthreads();  // slice writes visible before cross-lane readback
#pragma unroll
  for (int it = 0; it < 8; ++it) {
    int row = it * 8 + (lane >> 3);        // 0..63
    int colb = (lane & 7) * 8;             // 8 bf16 = 16B
    u16x8 v = *(const u16x8*)&slice[row * 64 + colb];
    *(u16x8*)&inter[(rowbase + wr * 64 + row) * (size_t)I_DIM + nb * 128 +
                    wn * 64 + colb] = v;
  }
}

// ---------------- FFN2: y[ks][slot] = inter @ w_out[K-half] (+bias at ks=0) --
// r14's proven 128x128 (256,3) kernel + KSPLIT=2 into PRIVATE partial buffers
// (no atomics; tile intensity and total staging traffic unchanged). ~1056
// active blocks = 4.1/CU restores multi-block barrier-drain hiding. A-MAJOR
// grid: 8 consecutive logicals share one A panel + K-half on one XCD.
__global__ void __launch_bounds__(256, 3) ffn2_kernel(
    const unsigned short* __restrict__ inter,
    const unsigned short* __restrict__ wout_t,  // [E][H][I]
    const float* __restrict__ b_out,            // [E][H]
    const int* __restrict__ counts,
    float* __restrict__ y) {                    // [2][YSLOTS][H]
  const int logical = xcd_swz(blockIdx.x, RB128 * 16);
  const int gk = logical >> 3;     // 0..143
  const int nb = logical & 7;
  const int g = gk >> 1;
  const int ks = gk & 1;
  int e, mb, cnt;
  if (!rb_lookup(counts, g, &e, &mb, &cnt)) return;
  (void)mb;

  __shared__ char smem[32768];  // A 16KB | B 16KB

  const int tid = threadIdx.x;
  const int wave = tid >> 6, lane = tid & 63;
  const int wr = wave >> 1, wn = wave & 1;  // 2M x 2N
  const int l16 = lane & 15, l4 = lane >> 4;
  const unsigned short* Bbase =
      wout_t + (size_t)e * H_DIM * I_DIM + (size_t)(nb * 128) * I_DIM;
  const size_t rowbase = (size_t)g * 128;
  float* yk = y + (size_t)ks * YSLOTS * H_DIM;

  f32x4 acc[4][4] = {};

  const int NKH = (I_DIM / 64) / 2;  // 32 K-steps per half
  for (int kt = ks * NKH; kt < (ks + 1) * NKH; ++kt) {
    __syncthreads();
#pragma unroll
    for (int it = 0; it < 4; ++it) {
      int id = it * 256 + tid;
      int r = id >> 3;
      int cs = (id & 7) ^ (r & 7);
      lds_load16(inter + (rowbase + r) * (size_t)I_DIM + kt * 64 + cs * 8,
                 smem + id * 16);
      lds_load16(Bbase + (size_t)r * I_DIM + kt * 64 + cs * 8,
                 smem + 16384 + id * 16);
    }
    __syncthreads();
#pragma unroll
    for (int kk = 0; kk < 2; ++kk) {
      bf16x8 af[4], bv[4];
#pragma unroll
      for (int m = 0; m < 4; ++m)
        af[m] = *lds_frag(smem, wr * 64 + m * 16 + l16, kk * 4 + l4);
#pragma unroll
      for (int n = 0; n < 4; ++n)
        bv[n] = *lds_frag(smem + 16384, wn * 64 + n * 16 + l16, kk * 4 + l4);
#pragma unroll
      for (int m = 0; m < 4; ++m)
#pragma unroll
        for (int n = 0; n < 4; ++n)
          acc[m][n] =
              __builtin_amdgcn_mfma_f32_16x16x32_bf16(af[m], bv[n], acc[m][n], 0, 0, 0);
    }
  }

  // ---- epilogue: two 32-row passes through per-wave 8KB LDS slice ----
  __syncthreads();
  float* slice = (float*)(smem + wave * 8192);
  float bias[4];
#pragma unroll
  for (int n = 0; n < 4; ++n)
    bias[n] = (ks == 0) ? b_out[e * H_DIM + nb * 128 + wn * 64 + n * 16 + l16]
                        : 0.f;
#pragma unroll
  for (int p = 0; p < 2; ++p) {
#pragma unroll
    for (int mm = 0; mm < 2; ++mm) {
      int m = p * 2 + mm;
#pragma unroll
      for (int n = 0; n < 4; ++n) {
#pragma unroll
        for (int j = 0; j < 4; ++j) {
          slice[(mm * 16 + l4 * 4 + j) * 64 + n * 16 + l16] =
              acc[m][n][j] + bias[n];
        }
      }
    }
    __syncthreads();  // slice writes visible before cross-lane readback
#pragma unroll
    for (int it = 0; it < 8; ++it) {
      int row = it * 4 + (lane >> 4);      // 0..31
      int col = (lane & 15) * 4;           // 4 floats = 16B
      float4 v = *(const float4*)&slice[row * 64 + col];
      *(float4*)&yk[(rowbase + wr * 64 + p * 32 + row) * (size_t)H_DIM +
                    nb * 128 + wn * 64 + col] = v;
    }
    __syncthreads();  // readback done before next pass overwrites slice
  }
}

// ---------------- combine: out[t] = w0*(y0+y1)[slot0] + w1*(y0+y1)[slot1] ----
__global__ void __launch_bounds__(256) combine_kernel(
    const float* __restrict__ y, const int* __restrict__ counts,
    const int* __restrict__ se, const float* __restrict__ wtok,
    float* __restrict__ out) {
  const int t = blockIdx.x;
  int poff[NE];
  int run = 0;
#pragma unroll
  for (int e = 0; e < NE; ++e) {
    poff[e] = run;
    run += (counts[e] + 127) & ~127;  // must match 128-row block padding
  }
  const float* y1 = y + (size_t)YSLOTS * H_DIM;
  int c0 = se[2 * t], c1 = se[2 * t + 1];
  float w0 = wtok[2 * t], w1 = wtok[2 * t + 1];
  size_t s0 = (size_t)(poff[c0 >> 20] + (c0 & 0xFFFFF)) * H_DIM;
  size_t s1 = (size_t)(poff[c1 >> 20] + (c1 & 0xFFFFF)) * H_DIM;
  int h = threadIdx.x * 4;
  float4 a0 = *reinterpret_cast<const float4*>(y + s0 + h);
  float4 a1 = *reinterpret_cast<const float4*>(y1 + s0 + h);
  float4 b0 = *reinterpret_cast<const float4*>(y + s1 + h);
  float4 b1 = *reinterpret_cast<const float4*>(y1 + s1 + h);
  float4 o;
  o.x = w0 * (a0.x + a1.x) + w1 * (b0.x + b1.x);
  o.y = w0 * (a0.y + a1.y) + w1 * (b0.y + b1.y);
  o.z = w0 * (a0.z + a1.z) + w1 * (b0.z + b1.z);
  o.w = w0 * (a0.w + a1.w) + w1 * (b0.w + b1.w);
  *reinterpret_cast<float4*>(out + (size_t)t * H_DIM + h) = o;
}

extern "C" void kernel_launch(void* const* d_in, const int* in_sizes, int n_in,
                              void* d_out, int out_size, void* d_ws, size_t ws_size,
                              hipStream_t stream) {
  const float* x     = (const float*)d_in[0];
  const float* rw    = (const float*)d_in[1];
  const float* w_in  = (const float*)d_in[2];
  const float* b_in  = (const float*)d_in[3];
  const float* w_out = (const float*)d_in[4];
  const float* b_out = (const float*)d_in[5];
  float* out = (float*)d_out;

  char* ws = (char*)d_ws;
  size_t off = 0;
  auto alloc = [&](size_t bytes) {
    char* p = ws + off;
    off = (off + bytes + 255) & ~(size_t)255;
    return p;
  };
  int* counts            = (int*)alloc(NE * 4);
  int* perm              = (int*)alloc((size_t)NE * CAP * 4);
  int* top2e             = (int*)alloc((size_t)T_TOK * 2 * 4);
  int* se                = (int*)alloc((size_t)T_TOK * 2 * 4);
  float* wtok            = (float*)alloc((size_t)T_TOK * 2 * 4);
  unsigned short* xb     = (unsigned short*)alloc((size_t)T_TOK * H_DIM * 2);
  unsigned short* win_t  = (unsigned short*)alloc((size_t)NE * H_DIM * I_DIM * 2);
  unsigned short* wout_t = (unsigned short*)alloc((size_t)NE * H_DIM * I_DIM * 2);
  unsigned short* inter  = (unsigned short*)alloc((size_t)(T_TOK * 2 + NE * 256) * I_DIM * 2);
  // y[2] overlays xb+win_t (both read-dead after K2's ffn1 part; rewritten by
  // prep before the next ffn1): 2*9216*1024*4 = 75,497,472 B
  //   = xb (8,388,608) + win_t (67,108,864) exactly.
  float* y = (float*)xb;
  if (off > ws_size) return;  // ws too small -> visible correctness failure

  prep_kernel<<<T_TOK + NE * 1024, 256, 0, stream>>>(x, rw, top2e, wtok, xb,
                                                     w_in, win_t);
  bucketize_kernel<<<NE, 1024, 0, stream>>>(top2e, counts, perm, se);
  ffn1_wout_kernel<<<32 * RB128 + NE * 1024, 256, 0, stream>>>(
      xb, win_t, b_in, counts, perm, inter, w_out, wout_t);
  ffn2_kernel<<<RB128 * 16, 256, 0, stream>>>(inter, wout_t, b_out, counts, y);
  combine_kernel<<<T_TOK, 256, 0, stream>>>(y, counts, se, wtok, out);
}

// Round 17
// 279.042 us; speedup vs baseline: 1.1221x; 1.0439x over previous
//
#include <hip/hip_runtime.h>
#include <hip/hip_bf16.h>
#include <stdint.h>

#define NE 8
#define T_TOK 4096
#define H_DIM 1024
#define I_DIM 4096
#define CAP 4096
#define RB128 72    // max total 128-row blocks: 8192/128 + 8 = 72
#define YSLOTS 9216 // max padded slot rows: 8192 + 8*127 -> round to 9216

typedef __attribute__((ext_vector_type(8))) short bf16x8;
typedef __attribute__((ext_vector_type(4))) float f32x4;
typedef __attribute__((ext_vector_type(8))) unsigned short u16x8;

__device__ __forceinline__ unsigned short f2bf(float f) {
  __hip_bfloat16 h = __float2bfloat16(f);
  return *reinterpret_cast<unsigned short*>(&h);
}

__device__ __forceinline__ float bf2f(unsigned short u) {
  unsigned int x = ((unsigned int)u) << 16;
  return *reinterpret_cast<float*>(&x);
}

__device__ __forceinline__ void lds_load16(const void* g, void* l) {
  __builtin_amdgcn_global_load_lds((__attribute__((address_space(1))) void*)g,
                                   (__attribute__((address_space(3))) void*)l,
                                   16, 0, 0);
}

// swizzled LDS fragment read: tile layout [rows][64 bf16] (128B rows, 8x16B
// chunks); content chunk cc of row lives at physical chunk cc ^ (row&7)
__device__ __forceinline__ const bf16x8* lds_frag(const char* base, int row,
                                                  int cc) {
  return (const bf16x8*)(base + row * 128 + ((cc ^ (row & 7)) << 4));
}

// bijective XCD swizzle (nwg % 8 == 0): each XCD owns a contiguous logical chunk
__device__ __forceinline__ int xcd_swz(int bid, int nwg) {
  return (bid & 7) * (nwg >> 3) + (bid >> 3);
}

// map flat 128-row block g -> (expert e, local block mb); rowbase is 128*g
__device__ __forceinline__ bool rb_lookup(const int* counts, int g, int* e_out,
                                          int* mb_out, int* cnt_out) {
  int acc = 0;
#pragma unroll
  for (int i = 0; i < NE; ++i) {
    int c = counts[i];
    int rb = (c + 127) >> 7;
    if (g < acc + rb) {
      *e_out = i;
      *mb_out = g - acc;
      *cnt_out = c;
      return true;
    }
    acc += rb;
  }
  return false;
}

// 64x64 transpose+convert tile: src f32 [R][C] region (r0,c0) -> dst bf16
// [C][R]. MLP-staged: all 4 float4 loads issued before LDS writes.
__device__ __forceinline__ void transpose_tile(const float* __restrict__ s,
                                               unsigned short* __restrict__ d,
                                               int R, int C, int r0, int c0,
                                               char* shm, int tid) {
  float(*tile)[65] = (float(*)[65])shm;
  const int lr = tid >> 4, lc = (tid & 15) << 2;
  float4 vv[4];
#pragma unroll
  for (int j = 0; j < 4; ++j)
    vv[j] = *reinterpret_cast<const float4*>(
        &s[(size_t)(r0 + j * 16 + lr) * C + c0 + lc]);
#pragma unroll
  for (int j = 0; j < 4; ++j) {
    tile[j * 16 + lr][lc + 0] = vv[j].x;
    tile[j * 16 + lr][lc + 1] = vv[j].y;
    tile[j * 16 + lr][lc + 2] = vv[j].z;
    tile[j * 16 + lr][lc + 3] = vv[j].w;
  }
  __syncthreads();
  const int oc = tid >> 3, orr = (tid & 7) << 3;
#pragma unroll
  for (int j = 0; j < 2; ++j) {
    int c = j * 32 + oc;
    u16x8 o;
#pragma unroll
    for (int k = 0; k < 8; ++k) o[k] = f2bf(tile[orr + k][c]);
    *reinterpret_cast<u16x8*>(&d[(size_t)(c0 + c) * R + r0 + orr]) = o;
  }
}

// ---------------- K1: router (NO atomics) U w_in transpose ----
__global__ void __launch_bounds__(256) prep_kernel(
    const float* __restrict__ x, const float* __restrict__ rw,
    int* __restrict__ top2e, float* __restrict__ wtok,
    unsigned short* __restrict__ xb, const float* __restrict__ w_in,
    unsigned short* __restrict__ win_t) {
  __shared__ char shm[16640];  // transpose tile; router uses first 128B
  const int bid = blockIdx.x;
  const int tid = threadIdx.x;

  if (bid < T_TOK) {
    // ---- router + x->bf16 for token t ----
    const int t = bid;
    float(*red)[NE] = (float(*)[NE])shm;
    float4 v = reinterpret_cast<const float4*>(x + (size_t)t * H_DIM)[tid];
    ushort4 o;
    o.x = f2bf(v.x); o.y = f2bf(v.y); o.z = f2bf(v.z); o.w = f2bf(v.w);
    reinterpret_cast<ushort4*>(xb + (size_t)t * H_DIM)[tid] = o;

    float part[NE];
#pragma unroll
    for (int e = 0; e < NE; ++e) {
      float4 w = reinterpret_cast<const float4*>(rw + (size_t)e * H_DIM)[tid];
      part[e] = v.x * w.x + v.y * w.y + v.z * w.z + v.w * w.w;
    }
    const int wave = tid >> 6, lane = tid & 63;
#pragma unroll
    for (int e = 0; e < NE; ++e) {
#pragma unroll
      for (int off = 32; off > 0; off >>= 1)
        part[e] += __shfl_xor(part[e], off);
    }
    if (lane == 0) {
#pragma unroll
      for (int e = 0; e < NE; ++e) red[wave][e] = part[e];
    }
    __syncthreads();
    if (tid == 0) {
      float acc[NE];
#pragma unroll
      for (int e = 0; e < NE; ++e)
        acc[e] = red[0][e] + red[1][e] + red[2][e] + red[3][e];
      int i0 = 0;
#pragma unroll
      for (int e = 1; e < NE; ++e)
        if (acc[e] > acc[i0]) i0 = e;
      int i1 = (i0 == 0) ? 1 : 0;
#pragma unroll
      for (int e = 0; e < NE; ++e)
        if (e != i0 && acc[e] > acc[i1]) i1 = e;
      float la = acc[i0], lb = acc[i1];
      float r = expf(lb - la);          // <= 1
      float wa = 1.f / (1.f + r);       // normalized top-2 softmax weights
      float wb = 1.f - wa;
      top2e[2 * t + 0] = i0;
      wtok[2 * t + 0] = wa;
      top2e[2 * t + 1] = i1;
      wtok[2 * t + 1] = wb;
    }
  } else {
    // ---- w_in [e][1024][4096] -> win_t [e][4096][1024] ----
    const int idx = bid - T_TOK;
    const int e = idx >> 10, rem = idx & 1023;
    const int c0 = (rem & 63) * 64, r0 = (rem >> 6) * 64;  // C=4096, R=1024
    transpose_tile(w_in + (size_t)e * H_DIM * I_DIM,
                   win_t + (size_t)e * H_DIM * I_DIM, H_DIM, I_DIM, r0, c0,
                   shm, tid);
  }
}

// ---------------- bucketize: deterministic counting-rank, no atomics ----
__global__ void __launch_bounds__(1024) bucketize_kernel(
    const int* __restrict__ top2e, int* __restrict__ counts,
    int* __restrict__ perm, int* __restrict__ se) {
  const int e = blockIdx.x;
  const int tid = threadIdx.x;
  __shared__ int wsum[16];
  int my[8];
  int cnt = 0;
#pragma unroll
  for (int j = 0; j < 8; ++j) {
    my[j] = top2e[tid * 8 + j];
    cnt += (my[j] == e) ? 1 : 0;
  }
  const int lane = tid & 63, wave = tid >> 6;
  int scan = cnt;  // inclusive wave scan
#pragma unroll
  for (int off = 1; off < 64; off <<= 1) {
    int v = __shfl_up(scan, off);
    if (lane >= off) scan += v;
  }
  if (lane == 63) wsum[wave] = scan;
  __syncthreads();
  int wbase = 0;
#pragma unroll
  for (int w = 0; w < 16; ++w)
    if (w < wave) wbase += wsum[w];
  int pos = wbase + scan - cnt;  // exclusive prefix for this thread
#pragma unroll
  for (int j = 0; j < 8; ++j) {
    if (my[j] == e) {
      int entry = tid * 8 + j;
      perm[e * CAP + pos] = entry >> 1;
      se[entry] = (e << 20) | pos;
      ++pos;
    }
  }
  if (tid == 1023) counts[e] = pos;
}

// ---------------- K2: ffn1 (2304 blocks, first) U w_out transpose (8192) ----
__global__ void __launch_bounds__(256, 3) ffn1_wout_kernel(
    const unsigned short* __restrict__ xb,
    const unsigned short* __restrict__ win_t,  // [E][I][H]
    const float* __restrict__ b_in,            // [E][I]
    const int* __restrict__ counts,
    const int* __restrict__ perm,
    unsigned short* __restrict__ inter,
    const float* __restrict__ w_out,
    unsigned short* __restrict__ wout_t) {
  __shared__ char smem[32768];
  const int bid = blockIdx.x;
  const int tid = threadIdx.x;

  if (bid >= 32 * RB128) {
    // ---- w_out [e][4096][1024] -> wout_t [e][1024][4096] ----
    const int idx = bid - 32 * RB128;
    const int e = idx >> 10, rem = idx & 1023;
    const int c0 = (rem & 15) * 64, r0 = (rem >> 4) * 64;  // C=1024, R=4096
    transpose_tile(w_out + (size_t)e * H_DIM * I_DIM,
                   wout_t + (size_t)e * H_DIM * I_DIM, I_DIM, H_DIM, r0, c0,
                   smem, tid);
    return;
  }

  const int logical = xcd_swz(bid, 32 * RB128);
  const int nb = logical / RB128;  // 0..31, consecutive logicals share B panel
  const int g = logical % RB128;
  int e, mb, cnt;
  if (!rb_lookup(counts, g, &e, &mb, &cnt)) return;

  int tokr[4];
#pragma unroll
  for (int it = 0; it < 4; ++it) {
    int r = (it * 256 + tid) >> 3;  // 0..127
    tokr[it] = perm[e * CAP + min(mb * 128 + r, cnt - 1)];
  }

  const int wave = tid >> 6, lane = tid & 63;
  const int wr = wave >> 1, wn = wave & 1;  // 2M x 2N
  const int l16 = lane & 15, l4 = lane >> 4;
  const unsigned short* Bbase =
      win_t + (size_t)e * I_DIM * H_DIM + (size_t)(nb * 128) * H_DIM;

  f32x4 acc[4][4] = {};

  const int NK = H_DIM / 64;  // 16
  for (int kt = 0; kt < NK; ++kt) {
    __syncthreads();  // all waves done reading smem (prev iter)
#pragma unroll
    for (int it = 0; it < 4; ++it) {
      int id = it * 256 + tid;
      int r = id >> 3;
      int cs = (id & 7) ^ (r & 7);  // T2: pre-swizzled source chunk
      lds_load16(xb + (size_t)tokr[it] * H_DIM + kt * 64 + cs * 8,
                 smem + id * 16);
      lds_load16(Bbase + (size_t)r * H_DIM + kt * 64 + cs * 8,
                 smem + 16384 + id * 16);
    }
    __syncthreads();  // compiler drains vmcnt(0) here (m97 asm behavior)
#pragma unroll
    for (int kk = 0; kk < 2; ++kk) {
      bf16x8 af[4], bv[4];
#pragma unroll
      for (int m = 0; m < 4; ++m)
        af[m] = *lds_frag(smem, wr * 64 + m * 16 + l16, kk * 4 + l4);
#pragma unroll
      for (int n = 0; n < 4; ++n)
        bv[n] = *lds_frag(smem + 16384, wn * 64 + n * 16 + l16, kk * 4 + l4);
#pragma unroll
      for (int m = 0; m < 4; ++m)
#pragma unroll
        for (int n = 0; n < 4; ++n)
          acc[m][n] =
              __builtin_amdgcn_mfma_f32_16x16x32_bf16(af[m], bv[n], acc[m][n], 0, 0, 0);
    }
  }

  // ---- epilogue: GELU, coalesce via per-wave 8KB LDS slice ----
  __syncthreads();  // all waves done with staging LDS
  const size_t rowbase = (size_t)g * 128;
  unsigned short* slice = (unsigned short*)(smem + wave * 8192);
#pragma unroll
  for (int n = 0; n < 4; ++n) {
    float bias = b_in[e * I_DIM + nb * 128 + wn * 64 + n * 16 + l16];
#pragma unroll
    for (int m = 0; m < 4; ++m) {
#pragma unroll
      for (int j = 0; j < 4; ++j) {
        float v = acc[m][n][j] + bias;
        // tanh-form GELU: v * sigmoid(1.59577(v + 0.044715 v^3)); |err| <~1e-3
        float t = __expf(-1.5957691216057308f * v - 0.07135481627f * v * v * v);
        float gg = v / (1.f + t);
        slice[(m * 16 + l4 * 4 + j) * 64 + n * 16 + l16] = f2bf(gg);
      }
    }
  }
  __syncthreads();  // slice writes visible before cross-lane readback
#pragma unroll
  for (int it = 0; it < 8; ++it) {
    int row = it * 8 + (lane >> 3);        // 0..63
    int colb = (lane & 7) * 8;             // 8 bf16 = 16B
    u16x8 v = *(const u16x8*)&slice[row * 64 + colb];
    *(u16x8*)&inter[(rowbase + wr * 64 + row) * (size_t)I_DIM + nb * 128 +
                    wn * 64 + colb] = v;
  }
}

// ---------------- FFN2: y[ks][slot] = inter @ w_out[K-half] (+bias at ks=0) --
// 128x128 (256,3) + KSPLIT=2 private partials (no atomics). y stored BF16
// (halves partial-buffer traffic; |y|<~2 -> quantization ~0.004, margin 4x).
__global__ void __launch_bounds__(256, 3) ffn2_kernel(
    const unsigned short* __restrict__ inter,
    const unsigned short* __restrict__ wout_t,  // [E][H][I]
    const float* __restrict__ b_out,            // [E][H]
    const int* __restrict__ counts,
    unsigned short* __restrict__ y) {           // [2][YSLOTS][H] bf16
  const int logical = xcd_swz(blockIdx.x, RB128 * 16);
  const int gk = logical >> 3;     // 0..143
  const int nb = logical & 7;
  const int g = gk >> 1;
  const int ks = gk & 1;
  int e, mb, cnt;
  if (!rb_lookup(counts, g, &e, &mb, &cnt)) return;
  (void)mb;

  __shared__ char smem[32768];  // A 16KB | B 16KB

  const int tid = threadIdx.x;
  const int wave = tid >> 6, lane = tid & 63;
  const int wr = wave >> 1, wn = wave & 1;  // 2M x 2N
  const int l16 = lane & 15, l4 = lane >> 4;
  const unsigned short* Bbase =
      wout_t + (size_t)e * H_DIM * I_DIM + (size_t)(nb * 128) * I_DIM;
  const size_t rowbase = (size_t)g * 128;
  unsigned short* yk = y + (size_t)ks * YSLOTS * H_DIM;

  f32x4 acc[4][4] = {};

  const int NKH = (I_DIM / 64) / 2;  // 32 K-steps per half
  for (int kt = ks * NKH; kt < (ks + 1) * NKH; ++kt) {
    __syncthreads();
#pragma unroll
    for (int it = 0; it < 4; ++it) {
      int id = it * 256 + tid;
      int r = id >> 3;
      int cs = (id & 7) ^ (r & 7);
      lds_load16(inter + (rowbase + r) * (size_t)I_DIM + kt * 64 + cs * 8,
                 smem + id * 16);
      lds_load16(Bbase + (size_t)r * I_DIM + kt * 64 + cs * 8,
                 smem + 16384 + id * 16);
    }
    __syncthreads();
#pragma unroll
    for (int kk = 0; kk < 2; ++kk) {
      bf16x8 af[4], bv[4];
#pragma unroll
      for (int m = 0; m < 4; ++m)
        af[m] = *lds_frag(smem, wr * 64 + m * 16 + l16, kk * 4 + l4);
#pragma unroll
      for (int n = 0; n < 4; ++n)
        bv[n] = *lds_frag(smem + 16384, wn * 64 + n * 16 + l16, kk * 4 + l4);
#pragma unroll
      for (int m = 0; m < 4; ++m)
#pragma unroll
        for (int n = 0; n < 4; ++n)
          acc[m][n] =
              __builtin_amdgcn_mfma_f32_16x16x32_bf16(af[m], bv[n], acc[m][n], 0, 0, 0);
    }
  }

  // ---- epilogue: two 32-row passes; per-wave 4KB bf16 slice; 16B stores ----
  __syncthreads();
  unsigned short* slice = (unsigned short*)(smem + wave * 8192);
  float bias[4];
#pragma unroll
  for (int n = 0; n < 4; ++n)
    bias[n] = (ks == 0) ? b_out[e * H_DIM + nb * 128 + wn * 64 + n * 16 + l16]
                        : 0.f;
#pragma unroll
  for (int p = 0; p < 2; ++p) {
#pragma unroll
    for (int mm = 0; mm < 2; ++mm) {
      int m = p * 2 + mm;
#pragma unroll
      for (int n = 0; n < 4; ++n) {
#pragma unroll
        for (int j = 0; j < 4; ++j) {
          slice[(mm * 16 + l4 * 4 + j) * 64 + n * 16 + l16] =
              f2bf(acc[m][n][j] + bias[n]);
        }
      }
    }
    __syncthreads();  // slice writes visible before cross-lane readback
#pragma unroll
    for (int it = 0; it < 4; ++it) {
      int row = it * 8 + (lane >> 3);      // 0..31
      int colb = (lane & 7) * 8;           // 8 bf16 = 16B
      u16x8 v = *(const u16x8*)&slice[row * 64 + colb];
      *(u16x8*)&yk[(rowbase + wr * 64 + p * 32 + row) * (size_t)H_DIM +
                   nb * 128 + wn * 64 + colb] = v;
    }
    __syncthreads();  // readback done before next pass overwrites slice
  }
}

// ---------------- combine: out[t] = w0*(y0+y1)[slot0] + w1*(y0+y1)[slot1] ----
// y is bf16; 128 threads x 8 elems each.
__global__ void __launch_bounds__(128) combine_kernel(
    const unsigned short* __restrict__ y, const int* __restrict__ counts,
    const int* __restrict__ se, const float* __restrict__ wtok,
    float* __restrict__ out) {
  const int t = blockIdx.x;
  int poff[NE];
  int run = 0;
#pragma unroll
  for (int e = 0; e < NE; ++e) {
    poff[e] = run;
    run += (counts[e] + 127) & ~127;  // must match 128-row block padding
  }
  const unsigned short* yh1 = y + (size_t)YSLOTS * H_DIM;
  int c0 = se[2 * t], c1 = se[2 * t + 1];
  float w0 = wtok[2 * t], w1 = wtok[2 * t + 1];
  size_t s0 = (size_t)(poff[c0 >> 20] + (c0 & 0xFFFFF)) * H_DIM;
  size_t s1 = (size_t)(poff[c1 >> 20] + (c1 & 0xFFFFF)) * H_DIM;
  int h = threadIdx.x * 8;
  u16x8 a0 = *reinterpret_cast<const u16x8*>(y + s0 + h);
  u16x8 a1 = *reinterpret_cast<const u16x8*>(yh1 + s0 + h);
  u16x8 b0 = *reinterpret_cast<const u16x8*>(y + s1 + h);
  u16x8 b1 = *reinterpret_cast<const u16x8*>(yh1 + s1 + h);
  float o[8];
#pragma unroll
  for (int k = 0; k < 8; ++k)
    o[k] = w0 * (bf2f(a0[k]) + bf2f(a1[k])) + w1 * (bf2f(b0[k]) + bf2f(b1[k]));
  float4 o0 = {o[0], o[1], o[2], o[3]};
  float4 o1 = {o[4], o[5], o[6], o[7]};
  *reinterpret_cast<float4*>(out + (size_t)t * H_DIM + h) = o0;
  *reinterpret_cast<float4*>(out + (size_t)t * H_DIM + h + 4) = o1;
}

extern "C" void kernel_launch(void* const* d_in, const int* in_sizes, int n_in,
                              void* d_out, int out_size, void* d_ws, size_t ws_size,
                              hipStream_t stream) {
  const float* x     = (const float*)d_in[0];
  const float* rw    = (const float*)d_in[1];
  const float* w_in  = (const float*)d_in[2];
  const float* b_in  = (const float*)d_in[3];
  const float* w_out = (const float*)d_in[4];
  const float* b_out = (const float*)d_in[5];
  float* out = (float*)d_out;

  char* ws = (char*)d_ws;
  size_t off = 0;
  auto alloc = [&](size_t bytes) {
    char* p = ws + off;
    off = (off + bytes + 255) & ~(size_t)255;
    return p;
  };
  int* counts            = (int*)alloc(NE * 4);
  int* perm              = (int*)alloc((size_t)NE * CAP * 4);
  int* top2e             = (int*)alloc((size_t)T_TOK * 2 * 4);
  int* se                = (int*)alloc((size_t)T_TOK * 2 * 4);
  float* wtok            = (float*)alloc((size_t)T_TOK * 2 * 4);
  unsigned short* xb     = (unsigned short*)alloc((size_t)T_TOK * H_DIM * 2);
  unsigned short* win_t  = (unsigned short*)alloc((size_t)NE * H_DIM * I_DIM * 2);
  unsigned short* wout_t = (unsigned short*)alloc((size_t)NE * H_DIM * I_DIM * 2);
  unsigned short* inter  = (unsigned short*)alloc((size_t)(T_TOK * 2 + NE * 256) * I_DIM * 2);
  // y[2] (bf16) overlays xb+win_t (both read-dead after K2's ffn1 part;
  // rewritten by prep before the next ffn1): 2*9216*1024*2 = 37.7MB < 72MB.
  unsigned short* y = xb;
  if (off > ws_size) return;  // ws too small -> visible correctness failure

  prep_kernel<<<T_TOK + NE * 1024, 256, 0, stream>>>(x, rw, top2e, wtok, xb,
                                                     w_in, win_t);
  bucketize_kernel<<<NE, 1024, 0, stream>>>(top2e, counts, perm, se);
  ffn1_wout_kernel<<<32 * RB128 + NE * 1024, 256, 0, stream>>>(
      xb, win_t, b_in, counts, perm, inter, w_out, wout_t);
  ffn2_kernel<<<RB128 * 16, 256, 0, stream>>>(inter, wout_t, b_out, counts, y);
  combine_kernel<<<T_TOK, 128, 0, stream>>>(y, counts, se, wtok, out);
}

// Round 18
// 275.571 us; speedup vs baseline: 1.1362x; 1.0126x over previous
//
#include <hip/hip_runtime.h>
#include <hip/hip_bf16.h>
#include <stdint.h>

#define NE 8
#define T_TOK 4096
#define H_DIM 1024
#define I_DIM 4096
#define CAP 4096
#define RB128 72    // max total 128-row blocks: 8192/128 + 8 = 72
#define YSLOTS 9216 // max padded slot rows: 8192 + 8*127 -> round to 9216

typedef __attribute__((ext_vector_type(8))) short bf16x8;
typedef __attribute__((ext_vector_type(4))) float f32x4;
typedef __attribute__((ext_vector_type(8))) unsigned short u16x8;

__device__ __forceinline__ unsigned short f2bf(float f) {
  __hip_bfloat16 h = __float2bfloat16(f);
  return *reinterpret_cast<unsigned short*>(&h);
}

__device__ __forceinline__ float bf2f(unsigned short u) {
  unsigned int x = ((unsigned int)u) << 16;
  return *reinterpret_cast<float*>(&x);
}

__device__ __forceinline__ void lds_load16(const void* g, void* l) {
  __builtin_amdgcn_global_load_lds((__attribute__((address_space(1))) void*)g,
                                   (__attribute__((address_space(3))) void*)l,
                                   16, 0, 0);
}

// swizzled LDS fragment read: tile layout [rows][64 bf16] (128B rows, 8x16B
// chunks); content chunk cc of row lives at physical chunk cc ^ (row&7)
__device__ __forceinline__ const bf16x8* lds_frag(const char* base, int row,
                                                  int cc) {
  return (const bf16x8*)(base + row * 128 + ((cc ^ (row & 7)) << 4));
}

// bijective XCD swizzle (nwg % 8 == 0): each XCD owns a contiguous logical chunk
__device__ __forceinline__ int xcd_swz(int bid, int nwg) {
  return (bid & 7) * (nwg >> 3) + (bid >> 3);
}

// map flat 128-row block g -> (expert e, local block mb); rowbase is 128*g
__device__ __forceinline__ bool rb_lookup(const int* counts, int g, int* e_out,
                                          int* mb_out, int* cnt_out) {
  int acc = 0;
#pragma unroll
  for (int i = 0; i < NE; ++i) {
    int c = counts[i];
    int rb = (c + 127) >> 7;
    if (g < acc + rb) {
      *e_out = i;
      *mb_out = g - acc;
      *cnt_out = c;
      return true;
    }
    acc += rb;
  }
  return false;
}

// 64x64 transpose+convert tile: src f32 [R][C] region (r0,c0) -> dst bf16
// [C][R]. MLP-staged: all 4 float4 loads issued before LDS writes.
__device__ __forceinline__ void transpose_tile(const float* __restrict__ s,
                                               unsigned short* __restrict__ d,
                                               int R, int C, int r0, int c0,
                                               char* shm, int tid) {
  float(*tile)[65] = (float(*)[65])shm;
  const int lr = tid >> 4, lc = (tid & 15) << 2;
  float4 vv[4];
#pragma unroll
  for (int j = 0; j < 4; ++j)
    vv[j] = *reinterpret_cast<const float4*>(
        &s[(size_t)(r0 + j * 16 + lr) * C + c0 + lc]);
#pragma unroll
  for (int j = 0; j < 4; ++j) {
    tile[j * 16 + lr][lc + 0] = vv[j].x;
    tile[j * 16 + lr][lc + 1] = vv[j].y;
    tile[j * 16 + lr][lc + 2] = vv[j].z;
    tile[j * 16 + lr][lc + 3] = vv[j].w;
  }
  __syncthreads();
  const int oc = tid >> 3, orr = (tid & 7) << 3;
#pragma unroll
  for (int j = 0; j < 2; ++j) {
    int c = j * 32 + oc;
    u16x8 o;
#pragma unroll
    for (int k = 0; k < 8; ++k) o[k] = f2bf(tile[orr + k][c]);
    *reinterpret_cast<u16x8*>(&d[(size_t)(c0 + c) * R + r0 + orr]) = o;
  }
}

// ---------------- K1: router (NO atomics) U w_in transpose ----
__global__ void __launch_bounds__(256) prep_kernel(
    const float* __restrict__ x, const float* __restrict__ rw,
    int* __restrict__ top2e, float* __restrict__ wtok,
    unsigned short* __restrict__ xb, const float* __restrict__ w_in,
    unsigned short* __restrict__ win_t) {
  __shared__ char shm[16640];  // transpose tile; router uses first 128B
  const int bid = blockIdx.x;
  const int tid = threadIdx.x;

  if (bid < T_TOK) {
    // ---- router + x->bf16 for token t ----
    const int t = bid;
    float(*red)[NE] = (float(*)[NE])shm;
    float4 v = reinterpret_cast<const float4*>(x + (size_t)t * H_DIM)[tid];
    ushort4 o;
    o.x = f2bf(v.x); o.y = f2bf(v.y); o.z = f2bf(v.z); o.w = f2bf(v.w);
    reinterpret_cast<ushort4*>(xb + (size_t)t * H_DIM)[tid] = o;

    float part[NE];
#pragma unroll
    for (int e = 0; e < NE; ++e) {
      float4 w = reinterpret_cast<const float4*>(rw + (size_t)e * H_DIM)[tid];
      part[e] = v.x * w.x + v.y * w.y + v.z * w.z + v.w * w.w;
    }
    const int wave = tid >> 6, lane = tid & 63;
#pragma unroll
    for (int e = 0; e < NE; ++e) {
#pragma unroll
      for (int off = 32; off > 0; off >>= 1)
        part[e] += __shfl_xor(part[e], off);
    }
    if (lane == 0) {
#pragma unroll
      for (int e = 0; e < NE; ++e) red[wave][e] = part[e];
    }
    __syncthreads();
    if (tid == 0) {
      float acc[NE];
#pragma unroll
      for (int e = 0; e < NE; ++e)
        acc[e] = red[0][e] + red[1][e] + red[2][e] + red[3][e];
      int i0 = 0;
#pragma unroll
      for (int e = 1; e < NE; ++e)
        if (acc[e] > acc[i0]) i0 = e;
      int i1 = (i0 == 0) ? 1 : 0;
#pragma unroll
      for (int e = 0; e < NE; ++e)
        if (e != i0 && acc[e] > acc[i1]) i1 = e;
      float la = acc[i0], lb = acc[i1];
      float r = expf(lb - la);          // <= 1
      float wa = 1.f / (1.f + r);       // normalized top-2 softmax weights
      float wb = 1.f - wa;
      top2e[2 * t + 0] = i0;
      wtok[2 * t + 0] = wa;
      top2e[2 * t + 1] = i1;
      wtok[2 * t + 1] = wb;
    }
  } else {
    // ---- w_in [e][1024][4096] -> win_t [e][4096][1024] ----
    const int idx = bid - T_TOK;
    const int e = idx >> 10, rem = idx & 1023;
    const int c0 = (rem & 63) * 64, r0 = (rem >> 6) * 64;  // C=4096, R=1024
    transpose_tile(w_in + (size_t)e * H_DIM * I_DIM,
                   win_t + (size_t)e * H_DIM * I_DIM, H_DIM, I_DIM, r0, c0,
                   shm, tid);
  }
}

// ---------------- bucketize: deterministic counting-rank, no atomics ----
__global__ void __launch_bounds__(1024) bucketize_kernel(
    const int* __restrict__ top2e, int* __restrict__ counts,
    int* __restrict__ perm, int* __restrict__ se) {
  const int e = blockIdx.x;
  const int tid = threadIdx.x;
  __shared__ int wsum[16];
  int my[8];
  int cnt = 0;
#pragma unroll
  for (int j = 0; j < 8; ++j) {
    my[j] = top2e[tid * 8 + j];
    cnt += (my[j] == e) ? 1 : 0;
  }
  const int lane = tid & 63, wave = tid >> 6;
  int scan = cnt;  // inclusive wave scan
#pragma unroll
  for (int off = 1; off < 64; off <<= 1) {
    int v = __shfl_up(scan, off);
    if (lane >= off) scan += v;
  }
  if (lane == 63) wsum[wave] = scan;
  __syncthreads();
  int wbase = 0;
#pragma unroll
  for (int w = 0; w < 16; ++w)
    if (w < wave) wbase += wsum[w];
  int pos = wbase + scan - cnt;  // exclusive prefix for this thread
#pragma unroll
  for (int j = 0; j < 8; ++j) {
    if (my[j] == e) {
      int entry = tid * 8 + j;
      perm[e * CAP + pos] = entry >> 1;
      se[entry] = (e << 20) | pos;
      ++pos;
    }
  }
  if (tid == 1023) counts[e] = pos;
}

// ---------------- K2: ffn1 (2304 blocks, first) U w_out transpose (8192) ----
// ffn1 grid is G-MAJOR (A-panel-major): consecutive logicals share one A
// panel (L2-hot per XCD); B panels stream once from HBM, re-read via LLC.
__global__ void __launch_bounds__(256, 3) ffn1_wout_kernel(
    const unsigned short* __restrict__ xb,
    const unsigned short* __restrict__ win_t,  // [E][I][H]
    const float* __restrict__ b_in,            // [E][I]
    const int* __restrict__ counts,
    const int* __restrict__ perm,
    unsigned short* __restrict__ inter,
    const float* __restrict__ w_out,
    unsigned short* __restrict__ wout_t) {
  __shared__ char smem[32768];
  const int bid = blockIdx.x;
  const int tid = threadIdx.x;

  if (bid >= 32 * RB128) {
    // ---- w_out [e][4096][1024] -> wout_t [e][1024][4096] ----
    const int idx = bid - 32 * RB128;
    const int e = idx >> 10, rem = idx & 1023;
    const int c0 = (rem & 15) * 64, r0 = (rem >> 4) * 64;  // C=1024, R=4096
    transpose_tile(w_out + (size_t)e * H_DIM * I_DIM,
                   wout_t + (size_t)e * H_DIM * I_DIM, I_DIM, H_DIM, r0, c0,
                   smem, tid);
    return;
  }

  const int logical = xcd_swz(bid, 32 * RB128);
  const int g = logical >> 5;     // consecutive logicals share A panel
  const int nb = logical & 31;
  int e, mb, cnt;
  if (!rb_lookup(counts, g, &e, &mb, &cnt)) return;

  int tokr[4];
#pragma unroll
  for (int it = 0; it < 4; ++it) {
    int r = (it * 256 + tid) >> 3;  // 0..127
    tokr[it] = perm[e * CAP + min(mb * 128 + r, cnt - 1)];
  }

  const int wave = tid >> 6, lane = tid & 63;
  const int wr = wave >> 1, wn = wave & 1;  // 2M x 2N
  const int l16 = lane & 15, l4 = lane >> 4;
  const unsigned short* Bbase =
      win_t + (size_t)e * I_DIM * H_DIM + (size_t)(nb * 128) * H_DIM;

  f32x4 acc[4][4] = {};

  const int NK = H_DIM / 64;  // 16
  for (int kt = 0; kt < NK; ++kt) {
    __syncthreads();  // all waves done reading smem (prev iter)
#pragma unroll
    for (int it = 0; it < 4; ++it) {
      int id = it * 256 + tid;
      int r = id >> 3;
      int cs = (id & 7) ^ (r & 7);  // T2: pre-swizzled source chunk
      lds_load16(xb + (size_t)tokr[it] * H_DIM + kt * 64 + cs * 8,
                 smem + id * 16);
      lds_load16(Bbase + (size_t)r * H_DIM + kt * 64 + cs * 8,
                 smem + 16384 + id * 16);
    }
    __syncthreads();  // compiler drains vmcnt(0) here (m97 asm behavior)
#pragma unroll
    for (int kk = 0; kk < 2; ++kk) {
      bf16x8 af[4], bv[4];
#pragma unroll
      for (int m = 0; m < 4; ++m)
        af[m] = *lds_frag(smem, wr * 64 + m * 16 + l16, kk * 4 + l4);
#pragma unroll
      for (int n = 0; n < 4; ++n)
        bv[n] = *lds_frag(smem + 16384, wn * 64 + n * 16 + l16, kk * 4 + l4);
#pragma unroll
      for (int m = 0; m < 4; ++m)
#pragma unroll
        for (int n = 0; n < 4; ++n)
          acc[m][n] =
              __builtin_amdgcn_mfma_f32_16x16x32_bf16(af[m], bv[n], acc[m][n], 0, 0, 0);
    }
  }

  // ---- epilogue: GELU, coalesce via per-wave 8KB LDS slice ----
  __syncthreads();  // all waves done with staging LDS
  const size_t rowbase = (size_t)g * 128;
  unsigned short* slice = (unsigned short*)(smem + wave * 8192);
#pragma unroll
  for (int n = 0; n < 4; ++n) {
    float bias = b_in[e * I_DIM + nb * 128 + wn * 64 + n * 16 + l16];
#pragma unroll
    for (int m = 0; m < 4; ++m) {
#pragma unroll
      for (int j = 0; j < 4; ++j) {
        float v = acc[m][n][j] + bias;
        // tanh-form GELU: v * sigmoid(1.59577(v + 0.044715 v^3)); |err| <~1e-3
        float t = __expf(-1.5957691216057308f * v - 0.07135481627f * v * v * v);
        float gg = v / (1.f + t);
        slice[(m * 16 + l4 * 4 + j) * 64 + n * 16 + l16] = f2bf(gg);
      }
    }
  }
  __syncthreads();  // slice writes visible before cross-lane readback
#pragma unroll
  for (int it = 0; it < 8; ++it) {
    int row = it * 8 + (lane >> 3);        // 0..63
    int colb = (lane & 7) * 8;             // 8 bf16 = 16B
    u16x8 v = *(const u16x8*)&slice[row * 64 + colb];
    *(u16x8*)&inter[(rowbase + wr * 64 + row) * (size_t)I_DIM + nb * 128 +
                    wn * 64 + colb] = v;
  }
}

// ---------------- FFN2: y[ks][slot] = inter @ w_out[K-half] (+bias at ks=0) --
// 128x128 (256,3) + KSPLIT=2 private partials (no atomics). y stored BF16
// (halves partial-buffer traffic; |y|<~2 -> quantization ~0.004, margin 4x).
__global__ void __launch_bounds__(256, 3) ffn2_kernel(
    const unsigned short* __restrict__ inter,
    const unsigned short* __restrict__ wout_t,  // [E][H][I]
    const float* __restrict__ b_out,            // [E][H]
    const int* __restrict__ counts,
    unsigned short* __restrict__ y) {           // [2][YSLOTS][H] bf16
  const int logical = xcd_swz(blockIdx.x, RB128 * 16);
  const int gk = logical >> 3;     // 0..143
  const int nb = logical & 7;
  const int g = gk >> 1;
  const int ks = gk & 1;
  int e, mb, cnt;
  if (!rb_lookup(counts, g, &e, &mb, &cnt)) return;
  (void)mb;

  __shared__ char smem[32768];  // A 16KB | B 16KB

  const int tid = threadIdx.x;
  const int wave = tid >> 6, lane = tid & 63;
  const int wr = wave >> 1, wn = wave & 1;  // 2M x 2N
  const int l16 = lane & 15, l4 = lane >> 4;
  const unsigned short* Bbase =
      wout_t + (size_t)e * H_DIM * I_DIM + (size_t)(nb * 128) * I_DIM;
  const size_t rowbase = (size_t)g * 128;
  unsigned short* yk = y + (size_t)ks * YSLOTS * H_DIM;

  f32x4 acc[4][4] = {};

  const int NKH = (I_DIM / 64) / 2;  // 32 K-steps per half
  for (int kt = ks * NKH; kt < (ks + 1) * NKH; ++kt) {
    __syncthreads();
#pragma unroll
    for (int it = 0; it < 4; ++it) {
      int id = it * 256 + tid;
      int r = id >> 3;
      int cs = (id & 7) ^ (r & 7);
      lds_load16(inter + (rowbase + r) * (size_t)I_DIM + kt * 64 + cs * 8,
                 smem + id * 16);
      lds_load16(Bbase + (size_t)r * I_DIM + kt * 64 + cs * 8,
                 smem + 16384 + id * 16);
    }
    __syncthreads();
#pragma unroll
    for (int kk = 0; kk < 2; ++kk) {
      bf16x8 af[4], bv[4];
#pragma unroll
      for (int m = 0; m < 4; ++m)
        af[m] = *lds_frag(smem, wr * 64 + m * 16 + l16, kk * 4 + l4);
#pragma unroll
      for (int n = 0; n < 4; ++n)
        bv[n] = *lds_frag(smem + 16384, wn * 64 + n * 16 + l16, kk * 4 + l4);
#pragma unroll
      for (int m = 0; m < 4; ++m)
#pragma unroll
        for (int n = 0; n < 4; ++n)
          acc[m][n] =
              __builtin_amdgcn_mfma_f32_16x16x32_bf16(af[m], bv[n], acc[m][n], 0, 0, 0);
    }
  }

  // ---- epilogue: two 32-row passes; per-wave 4KB bf16 slice; 16B stores ----
  __syncthreads();
  unsigned short* slice = (unsigned short*)(smem + wave * 8192);
  float bias[4];
#pragma unroll
  for (int n = 0; n < 4; ++n)
    bias[n] = (ks == 0) ? b_out[e * H_DIM + nb * 128 + wn * 64 + n * 16 + l16]
                        : 0.f;
#pragma unroll
  for (int p = 0; p < 2; ++p) {
#pragma unroll
    for (int mm = 0; mm < 2; ++mm) {
      int m = p * 2 + mm;
#pragma unroll
      for (int n = 0; n < 4; ++n) {
#pragma unroll
        for (int j = 0; j < 4; ++j) {
          slice[(mm * 16 + l4 * 4 + j) * 64 + n * 16 + l16] =
              f2bf(acc[m][n][j] + bias[n]);
        }
      }
    }
    __syncthreads();  // slice writes visible before cross-lane readback
#pragma unroll
    for (int it = 0; it < 4; ++it) {
      int row = it * 8 + (lane >> 3);      // 0..31
      int colb = (lane & 7) * 8;           // 8 bf16 = 16B
      u16x8 v = *(const u16x8*)&slice[row * 64 + colb];
      *(u16x8*)&yk[(rowbase + wr * 64 + p * 32 + row) * (size_t)H_DIM +
                   nb * 128 + wn * 64 + colb] = v;
    }
    __syncthreads();  // readback done before next pass overwrites slice
  }
}

// ---------------- combine: out[t] = w0*(y0+y1)[slot0] + w1*(y0+y1)[slot1] ----
// y is bf16; 128 threads x 8 elems each.
__global__ void __launch_bounds__(128) combine_kernel(
    const unsigned short* __restrict__ y, const int* __restrict__ counts,
    const int* __restrict__ se, const float* __restrict__ wtok,
    float* __restrict__ out) {
  const int t = blockIdx.x;
  int poff[NE];
  int run = 0;
#pragma unroll
  for (int e = 0; e < NE; ++e) {
    poff[e] = run;
    run += (counts[e] + 127) & ~127;  // must match 128-row block padding
  }
  const unsigned short* yh1 = y + (size_t)YSLOTS * H_DIM;
  int c0 = se[2 * t], c1 = se[2 * t + 1];
  float w0 = wtok[2 * t], w1 = wtok[2 * t + 1];
  size_t s0 = (size_t)(poff[c0 >> 20] + (c0 & 0xFFFFF)) * H_DIM;
  size_t s1 = (size_t)(poff[c1 >> 20] + (c1 & 0xFFFFF)) * H_DIM;
  int h = threadIdx.x * 8;
  u16x8 a0 = *reinterpret_cast<const u16x8*>(y + s0 + h);
  u16x8 a1 = *reinterpret_cast<const u16x8*>(yh1 + s0 + h);
  u16x8 b0 = *reinterpret_cast<const u16x8*>(y + s1 + h);
  u16x8 b1 = *reinterpret_cast<const u16x8*>(yh1 + s1 + h);
  float o[8];
#pragma unroll
  for (int k = 0; k < 8; ++k)
    o[k] = w0 * (bf2f(a0[k]) + bf2f(a1[k])) + w1 * (bf2f(b0[k]) + bf2f(b1[k]));
  float4 o0 = {o[0], o[1], o[2], o[3]};
  float4 o1 = {o[4], o[5], o[6], o[7]};
  *reinterpret_cast<float4*>(out + (size_t)t * H_DIM + h) = o0;
  *reinterpret_cast<float4*>(out + (size_t)t * H_DIM + h + 4) = o1;
}

extern "C" void kernel_launch(void* const* d_in, const int* in_sizes, int n_in,
                              void* d_out, int out_size, void* d_ws, size_t ws_size,
                              hipStream_t stream) {
  const float* x     = (const float*)d_in[0];
  const float* rw    = (const float*)d_in[1];
  const float* w_in  = (const float*)d_in[2];
  const float* b_in  = (const float*)d_in[3];
  const float* w_out = (const float*)d_in[4];
  const float* b_out = (const float*)d_in[5];
  float* out = (float*)d_out;

  char* ws = (char*)d_ws;
  size_t off = 0;
  auto alloc = [&](size_t bytes) {
    char* p = ws + off;
    off = (off + bytes + 255) & ~(size_t)255;
    return p;
  };
  int* counts            = (int*)alloc(NE * 4);
  int* perm              = (int*)alloc((size_t)NE * CAP * 4);
  int* top2e             = (int*)alloc((size_t)T_TOK * 2 * 4);
  int* se                = (int*)alloc((size_t)T_TOK * 2 * 4);
  float* wtok            = (float*)alloc((size_t)T_TOK * 2 * 4);
  unsigned short* xb     = (unsigned short*)alloc((size_t)T_TOK * H_DIM * 2);
  unsigned short* win_t  = (unsigned short*)alloc((size_t)NE * H_DIM * I_DIM * 2);
  unsigned short* wout_t = (unsigned short*)alloc((size_t)NE * H_DIM * I_DIM * 2);
  unsigned short* inter  = (unsigned short*)alloc((size_t)(T_TOK * 2 + NE * 256) * I_DIM * 2);
  // y[2] (bf16) overlays xb+win_t (both read-dead after K2's ffn1 part;
  // rewritten by prep before the next ffn1): 2*9216*1024*2 = 37.7MB < 72MB.
  unsigned short* y = xb;
  if (off > ws_size) return;  // ws too small -> visible correctness failure

  prep_kernel<<<T_TOK + NE * 1024, 256, 0, stream>>>(x, rw, top2e, wtok, xb,
                                                     w_in, win_t);
  bucketize_kernel<<<NE, 1024, 0, stream>>>(top2e, counts, perm, se);
  ffn1_wout_kernel<<<32 * RB128 + NE * 1024, 256, 0, stream>>>(
      xb, win_t, b_in, counts, perm, inter, w_out, wout_t);
  ffn2_kernel<<<RB128 * 16, 256, 0, stream>>>(inter, wout_t, b_out, counts, y);
  combine_kernel<<<T_TOK, 128, 0, stream>>>(y, counts, se, wtok, out);
}